// Round 13
// baseline (27613.403 us; speedup 1.0000x reference)
//
#include <hip/hip_runtime.h>
#include <math.h>

#define B 512
#define S 256
#define D 64
#define H 512
#define BH (B*H)

// ws layout: h32[2*BH f32] | c32[BH f32] | xatt[B*D f32]

__global__ __launch_bounds__(256) void init_zero(
    float* __restrict__ h32, float* __restrict__ c32)
{
    int i = blockIdx.x * blockDim.x + threadIdx.x;
    if (i < BH) { h32[i] = 0.f; c32[i] = 0.f; }
}

// Attention gate v3: 128 WGs x 4 rows, 4-wave k-split over [x|h|c] (1088).
// U traffic: 278KB/WG (one full read of Wa|Ua per WG), FMA overlaps stream.
__global__ __launch_bounds__(256) void attn_kernel(
    const float* __restrict__ x, const float* __restrict__ Wa,
    const float* __restrict__ Ua, const float* __restrict__ ba,
    const float* __restrict__ Va,
    const float* __restrict__ h32, const float* __restrict__ c32,
    float* __restrict__ xatt, int t)
{
    const int tid = threadIdx.x;
    const int lane = tid & 63;
    const int w = tid >> 6;
    const int b0 = blockIdx.x * 4;
    const int rd = t & 1;

    __shared__ float hc[4][1092];     // [row][k]: 0..63 x | 64..575 h | 576..1087 c
    __shared__ float part[4][4][64];  // [wave][row][d]
    __shared__ float ta[4][64];

    {   // stage: wave w stages row w (272 float4)
        const float4* xs = (const float4*)(x + ((size_t)(b0 + w)*S + t)*D);
        const float4* hs = (const float4*)(h32 + (size_t)rd*BH + (size_t)(b0 + w)*H);
        const float4* cs = (const float4*)(c32 + (size_t)(b0 + w)*H);
        for (int c = lane; c < 272; c += 64) {
            float4 v;
            if (c < 16)       v = xs[c];
            else if (c < 144) v = hs[c - 16];
            else              v = cs[c - 144];
            *(float4*)&hc[w][c*4] = v;
        }
    }
    __syncthreads();

    {   // phase 1: wave w covers k in [w*272, w*272+272), all 4 rows
        const int d = lane;
        const int k0 = w * 272;
        float a0 = 0.f, a1 = 0.f, a2 = 0.f, a3 = 0.f;
        #pragma unroll 4
        for (int kk = 0; kk < 272; kk += 4) {
            const int k = k0 + kk;
            float uv0 = (k     < 64) ? Wa[(k    )*D + d] : Ua[(size_t)(k      - 64)*D + d];
            float uv1 = (k + 1 < 64) ? Wa[(k + 1)*D + d] : Ua[(size_t)(k + 1 - 64)*D + d];
            float uv2 = (k + 2 < 64) ? Wa[(k + 2)*D + d] : Ua[(size_t)(k + 2 - 64)*D + d];
            float uv3 = (k + 3 < 64) ? Wa[(k + 3)*D + d] : Ua[(size_t)(k + 3 - 64)*D + d];
            float4 h0 = *(const float4*)&hc[0][k];
            float4 h1 = *(const float4*)&hc[1][k];
            float4 h2 = *(const float4*)&hc[2][k];
            float4 h3 = *(const float4*)&hc[3][k];
            a0 = fmaf(h0.x, uv0, a0); a0 = fmaf(h0.y, uv1, a0);
            a0 = fmaf(h0.z, uv2, a0); a0 = fmaf(h0.w, uv3, a0);
            a1 = fmaf(h1.x, uv0, a1); a1 = fmaf(h1.y, uv1, a1);
            a1 = fmaf(h1.z, uv2, a1); a1 = fmaf(h1.w, uv3, a1);
            a2 = fmaf(h2.x, uv0, a2); a2 = fmaf(h2.y, uv1, a2);
            a2 = fmaf(h2.z, uv2, a2); a2 = fmaf(h2.w, uv3, a2);
            a3 = fmaf(h3.x, uv0, a3); a3 = fmaf(h3.y, uv1, a3);
            a3 = fmaf(h3.z, uv2, a3); a3 = fmaf(h3.w, uv3, a3);
        }
        part[w][0][d] = a0;
        part[w][1][d] = a1;
        part[w][2][d] = a2;
        part[w][3][d] = a3;
    }
    __syncthreads();
    {   // phase 2: wave w reduces + tanh for row w
        float pre = ba[lane] + part[0][w][lane] + part[1][w][lane]
                  + part[2][w][lane] + part[3][w][lane];
        ta[w][lane] = tanhf(pre);
    }
    __syncthreads();
    {   // phase 3: wave w: @Va, softmax, write x_att for row w
        const int d = lane;
        float av = 0.f;
        #pragma unroll
        for (int k = 0; k < 64; k += 4) {
            float4 tv = *(const float4*)&ta[w][k];
            av = fmaf(tv.x, Va[(k    )*D + d], av);
            av = fmaf(tv.y, Va[(k + 1)*D + d], av);
            av = fmaf(tv.z, Va[(k + 2)*D + d], av);
            av = fmaf(tv.w, Va[(k + 3)*D + d], av);
        }
        float m = av;
        #pragma unroll
        for (int o = 32; o > 0; o >>= 1) m = fmaxf(m, __shfl_xor(m, o));
        float e = expf(av - m);
        float ssum = e;
        #pragma unroll
        for (int o = 32; o > 0; o >>= 1) ssum += __shfl_xor(ssum, o);
        xatt[(size_t)(b0 + w)*D + d] = (e / ssum) * hc[w][d];   // hc[w][d] = x
    }
}

// Gate GEMM + state update — R2 math verbatim, + double-buffered LDS with
// issue-early/write-late staging (1 barrier/chunk instead of 2).
// grid (16,16): bx = unit tile (32 units), by = row tile (32 rows).
// thread: tm = tid&7 (row group), tn = tid>>3 (unit 0..31); 4x4 acc.
__global__ __launch_bounds__(256) void gates_kernel(
    const float* __restrict__ Wih, const float* __restrict__ Whh,
    const float* __restrict__ bih, const float* __restrict__ bhh,
    const float* __restrict__ xatt, float* __restrict__ h32,
    float* __restrict__ c32, int t)
{
    const int tid = threadIdx.x;
    const int tm = tid & 7;
    const int tn = tid >> 3;
    const int u0 = blockIdx.x * 32;
    const int r0 = blockIdx.y * 32;
    const int u  = u0 + tn;

    __shared__ float h_lds[2][32][68];      // 2 x 8.7 KB
    __shared__ float w_lds[2][4][32][68];   // 2 x 34.8 KB  (total 87 KB)

    const int rd = t & 1, wrs = rd ^ 1;
    const float* __restrict__ hbuf_r = h32 + (size_t)rd*BH;
    float* __restrict__ hbuf_w = h32 + (size_t)wrs*BH;

    float acc[4][4];
    #pragma unroll
    for (int i = 0; i < 4; ++i)
        #pragma unroll
        for (int q = 0; q < 4; ++q) acc[i][q] = 0.f;

    float4 wreg[8];
    float4 hreg[2];

    auto issueW = [&](int kb) {
        #pragma unroll
        for (int it = 0; it < 8; ++it) {
            int j = tid + it*256;
            int f4c = j & 15, row = j >> 4;       // row 0..127
            int uu = row & 31, q = row >> 5;
            const float* src = (kb < 8)
                ? Whh + (size_t)(q*H + u0 + uu)*H + kb*64 + f4c*4
                : Wih + (size_t)(q*H + u0 + uu)*D + f4c*4;
            wreg[it] = *(const float4*)src;
        }
    };
    auto writeW = [&](int buf) {
        #pragma unroll
        for (int it = 0; it < 8; ++it) {
            int j = tid + it*256;
            int f4c = j & 15, row = j >> 4;
            int uu = row & 31, q = row >> 5;
            *(float4*)&w_lds[buf][q][uu][f4c*4] = wreg[it];
        }
    };
    auto issueH = [&](int kb) {
        #pragma unroll
        for (int it = 0; it < 2; ++it) {
            int j = tid + it*256;
            int f4c = j & 15, rl = j >> 4;        // rl 0..31
            const float* src = (kb < 8)
                ? hbuf_r + (size_t)(r0 + rl)*H + kb*64 + f4c*4
                : xatt + (size_t)(r0 + rl)*D + f4c*4;
            hreg[it] = *(const float4*)src;
        }
    };
    auto writeH = [&](int buf) {
        #pragma unroll
        for (int it = 0; it < 2; ++it) {
            int j = tid + it*256;
            int f4c = j & 15, rl = j >> 4;
            *(float4*)&h_lds[buf][rl][f4c*4] = hreg[it];
        }
    };

    issueW(0); issueH(0);
    writeW(0); writeH(0);
    __syncthreads();

    for (int kb = 0; kb < 9; ++kb) {
        const int buf = kb & 1;
        if (kb < 8) { issueW(kb + 1); issueH(kb + 1); }   // loads in flight
        #pragma unroll
        for (int k4 = 0; k4 < 16; ++k4) {
            float4 wv[4], hv[4];
            #pragma unroll
            for (int q = 0; q < 4; ++q)
                wv[q] = *(const float4*)&w_lds[buf][q][tn][k4*4];
            #pragma unroll
            for (int i = 0; i < 4; ++i)
                hv[i] = *(const float4*)&h_lds[buf][tm + 8*i][k4*4];
            #pragma unroll
            for (int i = 0; i < 4; ++i)
                #pragma unroll
                for (int q = 0; q < 4; ++q) {
                    acc[i][q] = fmaf(hv[i].x, wv[q].x, acc[i][q]);
                    acc[i][q] = fmaf(hv[i].y, wv[q].y, acc[i][q]);
                    acc[i][q] = fmaf(hv[i].z, wv[q].z, acc[i][q]);
                    acc[i][q] = fmaf(hv[i].w, wv[q].w, acc[i][q]);
                }
        }
        if (kb < 8) { writeW(buf ^ 1); writeH(buf ^ 1); }  // after compute
        __syncthreads();
    }

    float bsum[4];
    #pragma unroll
    for (int q = 0; q < 4; ++q) bsum[q] = bih[q*H + u] + bhh[q*H + u];

    #pragma unroll
    for (int i = 0; i < 4; ++i) {
        int b = r0 + tm + 8*i;
        float gi = acc[i][0] + bsum[0];
        float gf = acc[i][1] + bsum[1];
        float gg = acc[i][2] + bsum[2];
        float go = acc[i][3] + bsum[3];
        const size_t idx = (size_t)b*H + u;
        float c_old = c32[idx];
        float si = 1.f / (1.f + expf(-gi));
        float sf = 1.f / (1.f + expf(-gf));
        float so = 1.f / (1.f + expf(-go));
        float cn = sf * c_old + si * tanhf(gg);
        float hn = so * tanhf(cn);
        c32[idx] = cn;
        hbuf_w[idx] = hn;
    }
}

__global__ __launch_bounds__(256) void fc_kernel(
    const float* __restrict__ fcw, const float* __restrict__ fcb,
    const float* __restrict__ h32, float* __restrict__ out)
{
    const int b = blockIdx.x;
    __shared__ float hrow[H];
    const float* __restrict__ hp = h32 + (size_t)b*H;   // final h in slot 0 (S even)
    for (int k = threadIdx.x; k < H; k += 256) hrow[k] = hp[k];
    __syncthreads();
    int j = threadIdx.x;
    if (j < 24) {
        float a = fcb[j];
        #pragma unroll 8
        for (int k = 0; k < H; ++k) a += hrow[k] * fcw[j*H + k];
        out[b*24 + j] = a;
    }
}

extern "C" void kernel_launch(void* const* d_in, const int* in_sizes, int n_in,
                              void* d_out, int out_size, void* d_ws, size_t ws_size,
                              hipStream_t stream) {
    const float* x   = (const float*)d_in[0];
    const float* Wa  = (const float*)d_in[1];
    const float* Ua  = (const float*)d_in[2];
    const float* ba  = (const float*)d_in[3];
    const float* Va  = (const float*)d_in[4];
    const float* Wih = (const float*)d_in[5];
    const float* Whh = (const float*)d_in[6];
    const float* bih = (const float*)d_in[7];
    const float* bhh = (const float*)d_in[8];
    const float* fcw = (const float*)d_in[9];
    const float* fcb = (const float*)d_in[10];
    float* out = (float*)d_out;

    char* base = (char*)d_ws;
    float* h32  = (float*)(base);                       // 2*BH f32
    float* c32  = (float*)(base + (size_t)2*BH*4);      // BH f32 (in-place)
    float* xatt = (float*)(base + (size_t)3*BH*4);      // B*D f32

    hipLaunchKernelGGL(init_zero, dim3((BH + 255)/256), dim3(256), 0, stream,
                       h32, c32);
    for (int t = 0; t < S; ++t) {
        hipLaunchKernelGGL(attn_kernel, dim3(B/4), dim3(256), 0, stream,
                           x, Wa, Ua, ba, Va, h32, c32, xatt, t);
        hipLaunchKernelGGL(gates_kernel, dim3(16, 16), dim3(256), 0, stream,
                           Wih, Whh, bih, bhh, xatt, h32, c32, t);
    }
    hipLaunchKernelGGL(fc_kernel, dim3(B), dim3(256), 0, stream, fcw, fcb, h32, out);
}

// Round 14
// 12203.519 us; speedup vs baseline: 2.2627x; 2.2627x over previous
//
#include <hip/hip_runtime.h>
#include <math.h>

#define B 512
#define S 256
#define D 64
#define H 512
#define BH (B*H)

// ws layout: h32[2*BH f32] | c32[BH f32] | xatt[B*D f32]

__global__ __launch_bounds__(256) void init_zero(
    float* __restrict__ h32, float* __restrict__ c32)
{
    int i = blockIdx.x * blockDim.x + threadIdx.x;
    if (i < BH) { h32[i] = 0.f; c32[i] = 0.f; }
}

// Attention gate v3: 128 WGs x 4 rows, 4-wave k-split over [x|h|c] (1088).
// U traffic: 278KB/WG (one full read of Wa|Ua per WG), FMA overlaps stream.
__global__ __launch_bounds__(256) void attn_kernel(
    const float* __restrict__ x, const float* __restrict__ Wa,
    const float* __restrict__ Ua, const float* __restrict__ ba,
    const float* __restrict__ Va,
    const float* __restrict__ h32, const float* __restrict__ c32,
    float* __restrict__ xatt, int t)
{
    const int tid = threadIdx.x;
    const int lane = tid & 63;
    const int w = tid >> 6;
    const int b0 = blockIdx.x * 4;
    const int rd = t & 1;

    __shared__ float hc[4][1092];     // [row][k]: 0..63 x | 64..575 h | 576..1087 c
    __shared__ float part[4][4][64];  // [wave][row][d]
    __shared__ float ta[4][64];

    {   // stage: wave w stages row w (272 float4)
        const float4* xs = (const float4*)(x + ((size_t)(b0 + w)*S + t)*D);
        const float4* hs = (const float4*)(h32 + (size_t)rd*BH + (size_t)(b0 + w)*H);
        const float4* cs = (const float4*)(c32 + (size_t)(b0 + w)*H);
        for (int c = lane; c < 272; c += 64) {
            float4 v;
            if (c < 16)       v = xs[c];
            else if (c < 144) v = hs[c - 16];
            else              v = cs[c - 144];
            *(float4*)&hc[w][c*4] = v;
        }
    }
    __syncthreads();

    {   // phase 1: wave w covers k in [w*272, w*272+272), all 4 rows
        const int d = lane;
        const int k0 = w * 272;
        float a0 = 0.f, a1 = 0.f, a2 = 0.f, a3 = 0.f;
        #pragma unroll 4
        for (int kk = 0; kk < 272; kk += 4) {
            const int k = k0 + kk;
            float uv0 = (k     < 64) ? Wa[(k    )*D + d] : Ua[(size_t)(k      - 64)*D + d];
            float uv1 = (k + 1 < 64) ? Wa[(k + 1)*D + d] : Ua[(size_t)(k + 1 - 64)*D + d];
            float uv2 = (k + 2 < 64) ? Wa[(k + 2)*D + d] : Ua[(size_t)(k + 2 - 64)*D + d];
            float uv3 = (k + 3 < 64) ? Wa[(k + 3)*D + d] : Ua[(size_t)(k + 3 - 64)*D + d];
            float4 h0 = *(const float4*)&hc[0][k];
            float4 h1 = *(const float4*)&hc[1][k];
            float4 h2 = *(const float4*)&hc[2][k];
            float4 h3 = *(const float4*)&hc[3][k];
            a0 = fmaf(h0.x, uv0, a0); a0 = fmaf(h0.y, uv1, a0);
            a0 = fmaf(h0.z, uv2, a0); a0 = fmaf(h0.w, uv3, a0);
            a1 = fmaf(h1.x, uv0, a1); a1 = fmaf(h1.y, uv1, a1);
            a1 = fmaf(h1.z, uv2, a1); a1 = fmaf(h1.w, uv3, a1);
            a2 = fmaf(h2.x, uv0, a2); a2 = fmaf(h2.y, uv1, a2);
            a2 = fmaf(h2.z, uv2, a2); a2 = fmaf(h2.w, uv3, a2);
            a3 = fmaf(h3.x, uv0, a3); a3 = fmaf(h3.y, uv1, a3);
            a3 = fmaf(h3.z, uv2, a3); a3 = fmaf(h3.w, uv3, a3);
        }
        part[w][0][d] = a0;
        part[w][1][d] = a1;
        part[w][2][d] = a2;
        part[w][3][d] = a3;
    }
    __syncthreads();
    {   // phase 2: wave w reduces + tanh for row w
        float pre = ba[lane] + part[0][w][lane] + part[1][w][lane]
                  + part[2][w][lane] + part[3][w][lane];
        ta[w][lane] = tanhf(pre);
    }
    __syncthreads();
    {   // phase 3: wave w: @Va, softmax, write x_att for row w
        const int d = lane;
        float av = 0.f;
        #pragma unroll
        for (int k = 0; k < 64; k += 4) {
            float4 tv = *(const float4*)&ta[w][k];
            av = fmaf(tv.x, Va[(k    )*D + d], av);
            av = fmaf(tv.y, Va[(k + 1)*D + d], av);
            av = fmaf(tv.z, Va[(k + 2)*D + d], av);
            av = fmaf(tv.w, Va[(k + 3)*D + d], av);
        }
        float m = av;
        #pragma unroll
        for (int o = 32; o > 0; o >>= 1) m = fmaxf(m, __shfl_xor(m, o));
        float e = expf(av - m);
        float ssum = e;
        #pragma unroll
        for (int o = 32; o > 0; o >>= 1) ssum += __shfl_xor(ssum, o);
        xatt[(size_t)(b0 + w)*D + d] = (e / ssum) * hc[w][d];   // hc[w][d] = x
    }
}

// Gate GEMM + state update — R2 VERBATIM structure (measured 9.3us/dispatch,
// 83% of fp32 roofline): immediate load->LDS staging, 2 barriers/chunk,
// single-buffered 43.5 KB LDS. Only interface deltas: single-slot c32, fp32 xatt.
// grid (16,16): bx = unit tile (32 units), by = row tile (32 rows).
// thread: tm = tid&7 (row group), tn = tid>>3 (unit 0..31); 4x4 acc.
__global__ __launch_bounds__(256) void gates_kernel(
    const float* __restrict__ Wih, const float* __restrict__ Whh,
    const float* __restrict__ bih, const float* __restrict__ bhh,
    const float* __restrict__ xatt, float* __restrict__ h32,
    float* __restrict__ c32, int t)
{
    const int tm = threadIdx.x & 7;
    const int tn = threadIdx.x >> 3;
    const int u0 = blockIdx.x * 32;
    const int r0 = blockIdx.y * 32;
    const int u  = u0 + tn;

    __shared__ float h_lds[32][68];      // 68 = 64 + 4 pad
    __shared__ float w_lds[4][32][68];

    const int rd = t & 1, wrs = rd ^ 1;
    const float* __restrict__ hbuf_r = h32 + (size_t)rd*BH;
    float* __restrict__ hbuf_w = h32 + (size_t)wrs*BH;

    float acc[4][4];
    #pragma unroll
    for (int i = 0; i < 4; ++i)
        #pragma unroll
        for (int q = 0; q < 4; ++q) acc[i][q] = 0.f;

    // 8 k-blocks over (h, W_hh), then 1 block over (x_att, W_ih)
    for (int kb = 0; kb < 9; ++kb) {
        __syncthreads();
        {
            const float* src; int ldsrc, kofs;
            if (kb < 8) { src = Whh; ldsrc = H; kofs = kb*64; }
            else        { src = Wih; ldsrc = D; kofs = 0; }
            // stage W block: 128 rows x 16 float4
            #pragma unroll
            for (int it = 0; it < 8; ++it) {
                int j = threadIdx.x + it*256;
                int f4c = j & 15, row = j >> 4;       // row 0..127
                int uu = row & 31, q = row >> 5;
                float4 v = *reinterpret_cast<const float4*>(src + (size_t)(q*H + u0 + uu)*ldsrc + kofs + f4c*4);
                *reinterpret_cast<float4*>(&w_lds[q][uu][f4c*4]) = v;
            }
            // stage activation block: 32 rows x 16 float4
            const float* hsrc = (kb < 8) ? hbuf_r : xatt;
            int ldh   = (kb < 8) ? H : D;
            int kofs2 = (kb < 8) ? kb*64 : 0;
            #pragma unroll
            for (int it = 0; it < 2; ++it) {
                int j = threadIdx.x + it*256;
                int f4c = j & 15, rl = j >> 4;        // rl 0..31
                float4 v = *reinterpret_cast<const float4*>(hsrc + (size_t)(r0 + rl)*ldh + kofs2 + f4c*4);
                *reinterpret_cast<float4*>(&h_lds[rl][f4c*4]) = v;
            }
        }
        __syncthreads();
        #pragma unroll
        for (int k4 = 0; k4 < 16; ++k4) {
            float4 wv[4], hv[4];
            #pragma unroll
            for (int q = 0; q < 4; ++q)
                wv[q] = *reinterpret_cast<const float4*>(&w_lds[q][tn][k4*4]);
            #pragma unroll
            for (int i = 0; i < 4; ++i)
                hv[i] = *reinterpret_cast<const float4*>(&h_lds[tm + 8*i][k4*4]);
            #pragma unroll
            for (int i = 0; i < 4; ++i)
                #pragma unroll
                for (int q = 0; q < 4; ++q) {
                    acc[i][q] += hv[i].x * wv[q].x;
                    acc[i][q] += hv[i].y * wv[q].y;
                    acc[i][q] += hv[i].z * wv[q].z;
                    acc[i][q] += hv[i].w * wv[q].w;
                }
        }
    }

    float bsum[4];
    #pragma unroll
    for (int q = 0; q < 4; ++q) bsum[q] = bih[q*H + u] + bhh[q*H + u];

    #pragma unroll
    for (int i = 0; i < 4; ++i) {
        int b = r0 + tm + 8*i;
        float gi = acc[i][0] + bsum[0];
        float gf = acc[i][1] + bsum[1];
        float gg = acc[i][2] + bsum[2];
        float go = acc[i][3] + bsum[3];
        const size_t idx = (size_t)b*H + u;
        float c_old = c32[idx];
        float si = 1.f / (1.f + expf(-gi));
        float sf = 1.f / (1.f + expf(-gf));
        float so = 1.f / (1.f + expf(-go));
        float cn = sf * c_old + si * tanhf(gg);
        float hn = so * tanhf(cn);
        c32[idx] = cn;
        hbuf_w[idx] = hn;
    }
}

__global__ __launch_bounds__(256) void fc_kernel(
    const float* __restrict__ fcw, const float* __restrict__ fcb,
    const float* __restrict__ h32, float* __restrict__ out)
{
    const int b = blockIdx.x;
    __shared__ float hrow[H];
    const float* __restrict__ hp = h32 + (size_t)b*H;   // final h in slot 0 (S even)
    for (int k = threadIdx.x; k < H; k += 256) hrow[k] = hp[k];
    __syncthreads();
    int j = threadIdx.x;
    if (j < 24) {
        float a = fcb[j];
        #pragma unroll 8
        for (int k = 0; k < H; ++k) a += hrow[k] * fcw[j*H + k];
        out[b*24 + j] = a;
    }
}

extern "C" void kernel_launch(void* const* d_in, const int* in_sizes, int n_in,
                              void* d_out, int out_size, void* d_ws, size_t ws_size,
                              hipStream_t stream) {
    const float* x   = (const float*)d_in[0];
    const float* Wa  = (const float*)d_in[1];
    const float* Ua  = (const float*)d_in[2];
    const float* ba  = (const float*)d_in[3];
    const float* Va  = (const float*)d_in[4];
    const float* Wih = (const float*)d_in[5];
    const float* Whh = (const float*)d_in[6];
    const float* bih = (const float*)d_in[7];
    const float* bhh = (const float*)d_in[8];
    const float* fcw = (const float*)d_in[9];
    const float* fcb = (const float*)d_in[10];
    float* out = (float*)d_out;

    char* base = (char*)d_ws;
    float* h32  = (float*)(base);                       // 2*BH f32
    float* c32  = (float*)(base + (size_t)2*BH*4);      // BH f32 (in-place)
    float* xatt = (float*)(base + (size_t)3*BH*4);      // B*D f32

    hipLaunchKernelGGL(init_zero, dim3((BH + 255)/256), dim3(256), 0, stream,
                       h32, c32);
    for (int t = 0; t < S; ++t) {
        hipLaunchKernelGGL(attn_kernel, dim3(B/4), dim3(256), 0, stream,
                           x, Wa, Ua, ba, Va, h32, c32, xatt, t);
        hipLaunchKernelGGL(gates_kernel, dim3(16, 16), dim3(256), 0, stream,
                           Wih, Whh, bih, bhh, xatt, h32, c32, t);
    }
    hipLaunchKernelGGL(fc_kernel, dim3(B), dim3(256), 0, stream, fcw, fcb, h32, out);
}